// Round 24
// baseline (110.624 us; speedup 1.0000x reference)
//
#include <hip/hip_runtime.h>
#include <hip/hip_bf16.h>
#include <math.h>

#define NN 8192
#define INF_ 128
#define OUTF 64

typedef __attribute__((ext_vector_type(4))) float f32x4;
typedef __attribute__((ext_vector_type(4))) int i32x4;
typedef __attribute__((ext_vector_type(8))) unsigned short u16x8;
typedef __attribute__((ext_vector_type(8))) __bf16 bf16x8;

// barrier WITHOUT vmcnt drain: LDS visibility only (lgkmcnt).
#define BAR()                                                    \
    {                                                            \
        asm volatile("s_waitcnt lgkmcnt(0)" ::: "memory");       \
        __builtin_amdgcn_s_barrier();                            \
    }

__device__ __forceinline__ unsigned short f2bf(float f) {
    unsigned int u = __float_as_uint(f);
    u = (u + 0x7FFFu + ((u >> 16) & 1u)) >> 16;
    return (unsigned short)u;
}

// ---- Kernel 1 (FUSED): Wh = h@W; f1; bd = pack(exp(f2), exp(0.2 f2));
//      WhTs (lane-contiguous B-fragments) written directly from t_lds.
__global__ __launch_bounds__(256) void prep_kernel(
    const float* __restrict__ h, const float* __restrict__ W,
    const float* __restrict__ a, unsigned short* __restrict__ WhTs,
    float* __restrict__ f1, unsigned int* __restrict__ bd)
{
    __shared__ float W_lds[INF_ * OUTF];
    __shared__ float h_lds[32 * INF_];
    __shared__ unsigned short t_lds[OUTF * 34];

    const int t = threadIdx.x;
    const int rb = blockIdx.x * 32;

    {
        const float4* Ws = (const float4*)W;
        float4* Wd = (float4*)W_lds;
        #pragma unroll
        for (int q = 0; q < 8; ++q) Wd[t + 256 * q] = Ws[t + 256 * q];
        const float4* hs = (const float4*)(h + (size_t)rb * INF_);
        float4* hd = (float4*)h_lds;
        #pragma unroll
        for (int q = 0; q < 4; ++q) hd[t + 256 * q] = hs[t + 256 * q];
    }
    __syncthreads();

    const int lane = t & 63;
    const int w = t >> 6;

    float acc[8];
    #pragma unroll
    for (int q = 0; q < 8; ++q) acc[q] = 0.f;
    for (int k = 0; k < INF_; ++k) {
        const float wv = W_lds[k * OUTF + lane];
        #pragma unroll
        for (int q = 0; q < 8; ++q)
            acc[q] = fmaf(h_lds[(w * 8 + q) * INF_ + k], wv, acc[q]);
    }

    const float a1 = a[lane];
    const float a2 = a[OUTF + lane];
    #pragma unroll
    for (int q = 0; q < 8; ++q) {
        float s1 = acc[q] * a1;
        float s2 = acc[q] * a2;
        #pragma unroll
        for (int m = 1; m < 64; m <<= 1) {
            s1 += __shfl_xor(s1, m, 64);
            s2 += __shfl_xor(s2, m, 64);
        }
        if (lane == 0) {
            f1[rb + w * 8 + q] = s1;
            const unsigned int Bv = f2bf(expf(s2));
            const unsigned int Dv = f2bf(expf(0.2f * s2));
            bd[rb + w * 8 + q] = Bv | (Dv << 16);   // fused bd_kernel
        }
        t_lds[lane * 34 + w * 8 + q] = f2bf(acc[q]);
    }
    __syncthreads();
    {
        // fused repack: WhTs[ch*2048 + qd*512 + l*8 + e]
        //   = t_lds[(qd*16 + (l&15))*34 + (l>>4)*8 + e]
        const int qd = t >> 6, l = t & 63;
        const int c = qd * 16 + (l & 15);
        const int jr0 = (l >> 4) * 8;
        u16x8 v;
        #pragma unroll
        for (int e = 0; e < 8; ++e) v[e] = t_lds[c * 34 + jr0 + e];
        *(u16x8*)(WhTs + (size_t)blockIdx.x * 2048 + qd * 512 + l * 8) = v;
    }
}

// ---- Kernel 2: monolithic-wave fusion, 4 segments x 256 j with i32x4
//      (1 KB contiguous per row-request; half the request count of i32x2).
//      Mask mapping (r15/r17-verified): ballot(v[c]) bit l <-> j = s*256+4l+c;
//      bit for elem i of chunk cq: km[i&3] >> (8*cq + 2*g + (i>>2)).
__global__ __launch_bounds__(512, 4) void gatz_kernel(
    const int* __restrict__ adj, const unsigned short* __restrict__ WhTs,
    const float* __restrict__ f1, const unsigned int* __restrict__ bd,
    float* __restrict__ out)
{
    __shared__ float acc_lds[8 * 16 * OUTF];  // 32 KB partials
    __shared__ unsigned int bd_lds[NN];       // 32 KB (B,D) bf16 pairs
    __shared__ float l_lds[8 * 16];

    const int t = threadIdx.x;
    const int lane = t & 63;
    const int w = t >> 6;
    const int r = lane & 15;     // A-frag row / D feature
    const int g = lane >> 4;     // k-group
    const int row_base = blockIdx.x * 16;

    // stage bd (32 KB) cooperatively
    #pragma unroll
    for (int q = 0; q < 4; ++q)
        ((uint4*)bd_lds)[t + 512 * q] = ((const uint4*)bd)[t + 512 * q];

    const float f1r = f1[row_base + r];
    const float A = expf(f1r);               // e>0 branch row factor
    const float C = expf(0.2f * f1r);        // e<=0 branch row factor
    const unsigned int THb = (unsigned int)f2bf(expf(-f1r)); // B_j > THb <=> e > 0

    f32x4 accl = {0.f, 0.f, 0.f, 0.f};
    f32x4 acc[4];
    #pragma unroll
    for (int q = 0; q < 4; ++q) acc[q] = accl;

    u16x8 ones_u;
    #pragma unroll
    for (int i = 0; i < 8; ++i) ones_u[i] = 0x3F80;
    const bf16x8 bones = __builtin_bit_cast(bf16x8, ones_u);

    // wave w owns j-window [w*1024, w*1024+1024), all 16 rows.
    const int j0 = w * 1024;
    const int* base = adj + (size_t)row_base * NN + j0 + 4 * lane;
    const u16x8* wv = (const u16x8*)WhTs + lane; // + (ch*4+qd)*64

    // stage seg 0: 16 rows x 256 j, lane-contiguous i32x4 (1 KB per row-load)
    i32x4 st[16];
    #pragma unroll
    for (int rr = 0; rr < 16; ++rr)
        st[rr] = *(const i32x4*)(base + (size_t)rr * NN);

    BAR(); // bd_lds visible; adj loads stay in flight

    for (int s = 0; s < 4; ++s) {
        // ballot transpose: lane keeps the 4x64-bit masks of ITS row r.
        unsigned long long km[4];
        #pragma unroll
        for (int rr = 0; rr < 16; ++rr) {
            const i32x4 v = st[rr];
            const unsigned long long b0 = __ballot(v[0] > 0);
            const unsigned long long b1 = __ballot(v[1] > 0);
            const unsigned long long b2 = __ballot(v[2] > 0);
            const unsigned long long b3 = __ballot(v[3] > 0);
            if (rr == r) { km[0] = b0; km[1] = b1; km[2] = b2; km[3] = b3; }
        }
        // issue next segment's loads; they fly during the consume below
        if (s + 1 < 4) {
            #pragma unroll
            for (int rr = 0; rr < 16; ++rr)
                st[rr] = *(const i32x4*)(base + (size_t)rr * NN + (s + 1) * 256);
        }
        // consume 8 chunks of 32 j — exp-free table path
        #pragma unroll
        for (int cq = 0; cq < 8; ++cq) {
            const int jl = s * 256 + cq * 32;    // within wave window
            const int col = j0 + jl + g * 8;
            const int ch = (j0 + jl) >> 5;       // global 32-j chunk id
            const unsigned int shq = 8 * cq + 2 * g;
            const unsigned int e0 = (unsigned int)(km[0] >> shq) & 3u;
            const unsigned int e1 = (unsigned int)(km[1] >> shq) & 3u;
            const unsigned int e2 = (unsigned int)(km[2] >> shq) & 3u;
            const unsigned int e3 = (unsigned int)(km[3] >> shq) & 3u;
            const unsigned int eb[4] = {e0, e1, e2, e3};

            const uint4 bq0 = *(const uint4*)(bd_lds + col);
            const uint4 bq1 = *(const uint4*)(bd_lds + col + 4);
            const unsigned int bdv[8] = {bq0.x, bq0.y, bq0.z, bq0.w,
                                         bq1.x, bq1.y, bq1.z, bq1.w};

            u16x8 pb;
            #pragma unroll
            for (int i = 0; i < 8; ++i) {
                const unsigned int v = bdv[i];
                const unsigned int bb = v & 0xFFFFu;
                const bool up = bb > THb;                    // e > 0 ?
                const unsigned int sel = up ? bb : (v >> 16);
                const float f = __uint_as_float(sel << 16);  // bf16 -> f32
                const float as = up ? A : C;
                const unsigned int bit = (eb[i & 3] >> (i >> 2)) & 1u;
                const float p = bit ? f * as : 0.f;
                pb[i] = __builtin_bit_cast(unsigned short, __float2bfloat16(p));
            }

            const bf16x8 af = __builtin_bit_cast(bf16x8, pb);
            #pragma unroll
            for (int qd = 0; qd < 4; ++qd) {
                const bf16x8 bq = __builtin_bit_cast(bf16x8, wv[((size_t)ch * 4 + qd) * 64]);
                acc[qd] = __builtin_amdgcn_mfma_f32_16x16x32_bf16(af, bq, acc[qd], 0, 0, 0);
            }
            accl = __builtin_amdgcn_mfma_f32_16x16x32_bf16(af, bones, accl, 0, 0, 0);
        }
    }

    // D layout: col = lane&15 (feature), row = 4*g + q
    if (r == 0) {
        #pragma unroll
        for (int q = 0; q < 4; ++q) l_lds[w * 16 + 4 * g + q] = accl[q];
    }
    #pragma unroll
    for (int q = 0; q < 4; ++q) {
        const int m = 4 * g + q;
        #pragma unroll
        for (int qd = 0; qd < 4; ++qd)
            acc_lds[(w * 16 + m) * OUTF + qd * 16 + r] = acc[qd][q];
    }
    __syncthreads();

    // merge partials across the 8 waves: 1024 outputs, 2 per thread
    {
        #pragma unroll
        for (int hh = 0; hh < 2; ++hh) {
            const int idx = t + hh * 512;
            const int row = idx >> 6;
            const int col = idx & 63;
            float L = 0.f, o = 0.f;
            #pragma unroll
            for (int ww = 0; ww < 8; ++ww) {
                L += l_lds[ww * 16 + row];
                o += acc_lds[(ww * 16 + row) * OUTF + col];
            }
            o /= L;
            o = (o > 0.f) ? o : expm1f(o); // ELU
            out[(size_t)(row_base + row) * OUTF + col] = o;
        }
    }
}

extern "C" void kernel_launch(void* const* d_in, const int* in_sizes, int n_in,
                              void* d_out, int out_size, void* d_ws, size_t ws_size,
                              hipStream_t stream) {
    const float* h = (const float*)d_in[0];
    const int* adj = (const int*)d_in[1];
    const float* W = (const float*)d_in[2];
    const float* a = (const float*)d_in[3];
    float* out = (float*)d_out;

    char* ws = (char*)d_ws;
    unsigned short* WhTs = (unsigned short*)ws;                // 1 MB (lane-contiguous)
    float* f1 = (float*)(ws + (1 << 20));                      // 32 KB
    unsigned int* bd = (unsigned int*)(f1 + NN);               // 32 KB

    prep_kernel<<<NN / 32, 256, 0, stream>>>(h, W, a, WhTs, f1, bd);
    gatz_kernel<<<NN / 16, 512, 0, stream>>>(adj, WhTs, f1, bd, out);
}

// Round 25
// 70.939 us; speedup vs baseline: 1.5594x; 1.5594x over previous
//
#include <hip/hip_runtime.h>
#include <hip/hip_bf16.h>
#include <math.h>

#define NN 8192
#define INF_ 128
#define OUTF 64

typedef __attribute__((ext_vector_type(4))) float f32x4;
typedef __attribute__((ext_vector_type(2))) int i32x2;
typedef __attribute__((ext_vector_type(8))) unsigned short u16x8;
typedef __attribute__((ext_vector_type(8))) __bf16 bf16x8;

// barrier WITHOUT vmcnt drain: LDS visibility only (lgkmcnt).
#define BAR()                                                    \
    {                                                            \
        asm volatile("s_waitcnt lgkmcnt(0)" ::: "memory");       \
        __builtin_amdgcn_s_barrier();                            \
    }

__device__ __forceinline__ unsigned short f2bf(float f) {
    unsigned int u = __float_as_uint(f);
    u = (u + 0x7FFFu + ((u >> 16) & 1u)) >> 16;
    return (unsigned short)u;
}

// ---- Kernel 1 (FUSED): Wh = h@W; f1; bd = pack(exp(f2), exp(0.2 f2));
//      WhTs (lane-contiguous B-fragments) written directly from t_lds.
__global__ __launch_bounds__(256) void prep_kernel(
    const float* __restrict__ h, const float* __restrict__ W,
    const float* __restrict__ a, unsigned short* __restrict__ WhTs,
    float* __restrict__ f1, unsigned int* __restrict__ bd)
{
    __shared__ float W_lds[INF_ * OUTF];
    __shared__ float h_lds[32 * INF_];
    __shared__ unsigned short t_lds[OUTF * 34];

    const int t = threadIdx.x;
    const int rb = blockIdx.x * 32;

    {
        const float4* Ws = (const float4*)W;
        float4* Wd = (float4*)W_lds;
        #pragma unroll
        for (int q = 0; q < 8; ++q) Wd[t + 256 * q] = Ws[t + 256 * q];
        const float4* hs = (const float4*)(h + (size_t)rb * INF_);
        float4* hd = (float4*)h_lds;
        #pragma unroll
        for (int q = 0; q < 4; ++q) hd[t + 256 * q] = hs[t + 256 * q];
    }
    __syncthreads();

    const int lane = t & 63;
    const int w = t >> 6;

    float acc[8];
    #pragma unroll
    for (int q = 0; q < 8; ++q) acc[q] = 0.f;
    for (int k = 0; k < INF_; ++k) {
        const float wv = W_lds[k * OUTF + lane];
        #pragma unroll
        for (int q = 0; q < 8; ++q)
            acc[q] = fmaf(h_lds[(w * 8 + q) * INF_ + k], wv, acc[q]);
    }

    const float a1 = a[lane];
    const float a2 = a[OUTF + lane];
    #pragma unroll
    for (int q = 0; q < 8; ++q) {
        float s1 = acc[q] * a1;
        float s2 = acc[q] * a2;
        #pragma unroll
        for (int m = 1; m < 64; m <<= 1) {
            s1 += __shfl_xor(s1, m, 64);
            s2 += __shfl_xor(s2, m, 64);
        }
        if (lane == 0) {
            f1[rb + w * 8 + q] = s1;
            const unsigned int Bv = f2bf(expf(s2));
            const unsigned int Dv = f2bf(expf(0.2f * s2));
            bd[rb + w * 8 + q] = Bv | (Dv << 16);   // fused bd_kernel
        }
        t_lds[lane * 34 + w * 8 + q] = f2bf(acc[q]);
    }
    __syncthreads();
    {
        // fused repack: WhTs[ch*2048 + qd*512 + l*8 + e]
        //   = t_lds[(qd*16 + (l&15))*34 + (l>>4)*8 + e]
        const int qd = t >> 6, l = t & 63;
        const int c = qd * 16 + (l & 15);
        const int jr0 = (l >> 4) * 8;
        u16x8 v;
        #pragma unroll
        for (int e = 0; e < 8; ++e) v[e] = t_lds[c * 34 + jr0 + e];
        *(u16x8*)(WhTs + (size_t)blockIdx.x * 2048 + qd * 512 + l * 8) = v;
    }
}

// ---- Kernel 2: monolithic-wave fusion. Mr dropped entirely: the softmax
//      ratio acc/L is scale-invariant per row, so A = exp(f1), C = exp(0.2 f1)
//      need no max subtraction (p <= ~e^40, safely in fp32/bf16 range).
__global__ __launch_bounds__(512) void gatz_kernel(
    const int* __restrict__ adj, const unsigned short* __restrict__ WhTs,
    const float* __restrict__ f1, const unsigned int* __restrict__ bd,
    float* __restrict__ out)
{
    __shared__ float acc_lds[8 * 16 * OUTF];  // 32 KB partials
    __shared__ unsigned int bd_lds[NN];       // 32 KB (B,D) bf16 pairs
    __shared__ float l_lds[8 * 16];

    const int t = threadIdx.x;
    const int lane = t & 63;
    const int w = t >> 6;
    const int r = lane & 15;     // A-frag row / D feature
    const int g = lane >> 4;     // k-group
    const int row_base = blockIdx.x * 16;

    // stage bd (32 KB) cooperatively
    #pragma unroll
    for (int q = 0; q < 4; ++q)
        ((uint4*)bd_lds)[t + 512 * q] = ((const uint4*)bd)[t + 512 * q];

    const float f1r = f1[row_base + r];
    const float A = expf(f1r);               // e>0 branch row factor
    const float C = expf(0.2f * f1r);        // e<=0 branch row factor
    const unsigned int THb = (unsigned int)f2bf(expf(-f1r)); // B_j > THb <=> e > 0

    f32x4 accl = {0.f, 0.f, 0.f, 0.f};
    f32x4 acc[4];
    #pragma unroll
    for (int q = 0; q < 4; ++q) acc[q] = accl;

    u16x8 ones_u;
    #pragma unroll
    for (int i = 0; i < 8; ++i) ones_u[i] = 0x3F80;
    const bf16x8 bones = __builtin_bit_cast(bf16x8, ones_u);

    // wave w owns j-window [w*1024, w*1024+1024), all 16 rows.
    const int j0 = w * 1024;
    const int* base = adj + (size_t)row_base * NN + j0 + 2 * lane;
    const u16x8* wv = (const u16x8*)WhTs + lane; // + (ch*4+qd)*64

    // stage seg 0: 16 rows x 128 j, lane-contiguous i32x2
    i32x2 st[16];
    #pragma unroll
    for (int rr = 0; rr < 16; ++rr)
        st[rr] = *(const i32x2*)(base + (size_t)rr * NN);

    BAR(); // bd_lds visible; adj loads stay in flight

    for (int s = 0; s < 8; ++s) {
        // ballot transpose: lane keeps the 2x64-bit masks of ITS row r.
        unsigned long long k0 = 0ull, k1 = 0ull;
        #pragma unroll
        for (int rr = 0; rr < 16; ++rr) {
            const i32x2 v = st[rr];
            const unsigned long long b0 = __ballot(v[0] > 0);
            const unsigned long long b1 = __ballot(v[1] > 0);
            if (rr == r) { k0 = b0; k1 = b1; }
        }
        // issue next segment's loads; they fly during the consume below
        if (s + 1 < 8) {
            #pragma unroll
            for (int rr = 0; rr < 16; ++rr)
                st[rr] = *(const i32x2*)(base + (size_t)rr * NN + (s + 1) * 128);
        }
        // consume 4 chunks of 32 j — exp-free table path
        #pragma unroll
        for (int cc = 0; cc < 4; ++cc) {
            const int jl = s * 128 + cc * 32;    // within wave window
            const int col = j0 + jl + g * 8;
            const int ch = (j0 + jl) >> 5;       // global 32-j chunk id
            const unsigned int sh = 16 * cc + 4 * g;
            const unsigned int m0 = (unsigned int)(k0 >> sh) & 0xFu; // even i
            const unsigned int m1 = (unsigned int)(k1 >> sh) & 0xFu; // odd  i
            const uint4 bq0 = *(const uint4*)(bd_lds + col);
            const uint4 bq1 = *(const uint4*)(bd_lds + col + 4);
            const unsigned int bdv[8] = {bq0.x, bq0.y, bq0.z, bq0.w,
                                         bq1.x, bq1.y, bq1.z, bq1.w};

            u16x8 pb;
            #pragma unroll
            for (int i = 0; i < 8; ++i) {
                const unsigned int v = bdv[i];
                const unsigned int bb = v & 0xFFFFu;
                const bool up = bb > THb;                    // e > 0 ?
                const unsigned int sel = up ? bb : (v >> 16);
                const float f = __uint_as_float(sel << 16);  // bf16 -> f32
                const float as = up ? A : C;
                const unsigned int bit = (((i & 1) ? m1 : m0) >> (i >> 1)) & 1u;
                const float p = bit ? f * as : 0.f;
                pb[i] = __builtin_bit_cast(unsigned short, __float2bfloat16(p));
            }

            const bf16x8 af = __builtin_bit_cast(bf16x8, pb);
            #pragma unroll
            for (int qd = 0; qd < 4; ++qd) {
                const bf16x8 bq = __builtin_bit_cast(bf16x8, wv[((size_t)ch * 4 + qd) * 64]);
                acc[qd] = __builtin_amdgcn_mfma_f32_16x16x32_bf16(af, bq, acc[qd], 0, 0, 0);
            }
            accl = __builtin_amdgcn_mfma_f32_16x16x32_bf16(af, bones, accl, 0, 0, 0);
        }
    }

    // D layout: col = lane&15 (feature), row = 4*g + q
    if (r == 0) {
        #pragma unroll
        for (int q = 0; q < 4; ++q) l_lds[w * 16 + 4 * g + q] = accl[q];
    }
    #pragma unroll
    for (int q = 0; q < 4; ++q) {
        const int m = 4 * g + q;
        #pragma unroll
        for (int qd = 0; qd < 4; ++qd)
            acc_lds[(w * 16 + m) * OUTF + qd * 16 + r] = acc[qd][q];
    }
    __syncthreads();

    // merge partials across the 8 waves: 1024 outputs, 2 per thread
    {
        #pragma unroll
        for (int hh = 0; hh < 2; ++hh) {
            const int idx = t + hh * 512;
            const int row = idx >> 6;
            const int col = idx & 63;
            float L = 0.f, o = 0.f;
            #pragma unroll
            for (int ww = 0; ww < 8; ++ww) {
                L += l_lds[ww * 16 + row];
                o += acc_lds[(ww * 16 + row) * OUTF + col];
            }
            o /= L;
            o = (o > 0.f) ? o : expm1f(o); // ELU
            out[(size_t)(row_base + row) * OUTF + col] = o;
        }
    }
}

extern "C" void kernel_launch(void* const* d_in, const int* in_sizes, int n_in,
                              void* d_out, int out_size, void* d_ws, size_t ws_size,
                              hipStream_t stream) {
    const float* h = (const float*)d_in[0];
    const int* adj = (const int*)d_in[1];
    const float* W = (const float*)d_in[2];
    const float* a = (const float*)d_in[3];
    float* out = (float*)d_out;

    char* ws = (char*)d_ws;
    unsigned short* WhTs = (unsigned short*)ws;                // 1 MB (lane-contiguous)
    float* f1 = (float*)(ws + (1 << 20));                      // 32 KB
    unsigned int* bd = (unsigned int*)(f1 + NN);               // 32 KB

    prep_kernel<<<NN / 32, 256, 0, stream>>>(h, W, a, WhTs, f1, bd);
    gatz_kernel<<<NN / 16, 512, 0, stream>>>(adj, WhTs, f1, bd, out);
}